// Round 1
// baseline (188.093 us; speedup 1.0000x reference)
//
#include <hip/hip_runtime.h>
#include <hip/hip_bf16.h>

typedef __attribute__((ext_vector_type(8))) short short8;
typedef __attribute__((ext_vector_type(4))) float f32x4;
typedef unsigned short ushort_t;

#define NFRAMES 8
#define HD 32
#define CDIM 384
#define NH 12
#define NTOK 2048
#define BATCH 2
#define NROWS 4096
#define QKCOLS 768

static __device__ __forceinline__ ushort_t f2bf(float f) {
    __hip_bfloat16 h = __float2bfloat16(f);
    return *reinterpret_cast<ushort_t*>(&h);
}
static __device__ __forceinline__ float bf2f(ushort_t u) {
    unsigned int v = ((unsigned int)u) << 16;
    return __uint_as_float(v);
}

// ---------------- pack x: [16,384,16,16] f32 -> Xt[4096][384] bf16 ----------------
__global__ __launch_bounds__(256) void pack_x_kernel(const float* __restrict__ x,
                                                     ushort_t* __restrict__ Xt) {
    __shared__ float lds[32 * 256];
    int bt = blockIdx.x;    // 0..15
    int cblk = blockIdx.y;  // 0..11
    int tid = threadIdx.x;  // 0..255
    int c0 = cblk * 32;
    const float* src = x + ((long)bt * CDIM + c0) * 256;
#pragma unroll
    for (int i = 0; i < 32; ++i)
        lds[i * 256 + tid] = src[i * 256 + tid];
    __syncthreads();
    int b = bt >> 3, t = bt & 7;
    long n = (long)b * NTOK + t * 256 + tid;
    uint4* dst = reinterpret_cast<uint4*>(Xt + n * CDIM + c0);
#pragma unroll
    for (int k = 0; k < 4; ++k) {
        unsigned int vv[4];
#pragma unroll
        for (int q = 0; q < 4; ++q) {
            ushort_t lo = f2bf(lds[(k * 8 + q * 2) * 256 + tid]);
            ushort_t hi = f2bf(lds[(k * 8 + q * 2 + 1) * 256 + tid]);
            vv[q] = (unsigned int)lo | ((unsigned int)hi << 16);
        }
        dst[k] = make_uint4(vv[0], vv[1], vv[2], vv[3]);
    }
}

// ---------------- pack w: qk_w [768][384] f32 -> bf16, q-half pre-scaled ----------------
__global__ __launch_bounds__(256) void pack_w_kernel(const float* __restrict__ w,
                                                     ushort_t* __restrict__ Wb) {
    int idx = blockIdx.x * 256 + threadIdx.x;
    if (idx >= QKCOLS * CDIM) return;
    int j = idx / CDIM;
    float scale = (j < CDIM) ? 0.17677669529663687f : 1.0f;  // 32^-0.5 folded into Wq
    Wb[idx] = f2bf(w[idx] * scale);
}

// ---------------- projection: QK[4096][768] = Xt[4096][384] @ Wb^T ----------------
__global__ __launch_bounds__(256) void proj_kernel(const ushort_t* __restrict__ Xt,
                                                   const ushort_t* __restrict__ Wb,
                                                   ushort_t* __restrict__ QK) {
    int tid = threadIdx.x;
    int lane = tid & 63;
    int wid = blockIdx.x * 4 + (tid >> 6);  // 0..3071
    int mb = wid / 24, nb = wid % 24;       // 128 x 24 wave tiles of 32x32
    int r16 = lane & 15, g = lane >> 4;
    const short8* A0 = reinterpret_cast<const short8*>(Xt + (mb * 32 + r16) * CDIM + g * 8);
    const short8* A1 = reinterpret_cast<const short8*>(Xt + (mb * 32 + 16 + r16) * CDIM + g * 8);
    const short8* B0 = reinterpret_cast<const short8*>(Wb + (nb * 32 + r16) * CDIM + g * 8);
    const short8* B1 = reinterpret_cast<const short8*>(Wb + (nb * 32 + 16 + r16) * CDIM + g * 8);
    f32x4 acc00{}, acc01{}, acc10{}, acc11{};
#pragma unroll
    for (int kk = 0; kk < 12; ++kk) {
        short8 a0 = A0[kk * 4];
        short8 a1 = A1[kk * 4];
        short8 b0 = B0[kk * 4];
        short8 b1 = B1[kk * 4];
        acc00 = __builtin_amdgcn_mfma_f32_16x16x32_bf16(a0, b0, acc00, 0, 0, 0);
        acc01 = __builtin_amdgcn_mfma_f32_16x16x32_bf16(a0, b1, acc01, 0, 0, 0);
        acc10 = __builtin_amdgcn_mfma_f32_16x16x32_bf16(a1, b0, acc10, 0, 0, 0);
        acc11 = __builtin_amdgcn_mfma_f32_16x16x32_bf16(a1, b1, acc11, 0, 0, 0);
    }
    int rowb = mb * 32 + g * 4;
    int colb = nb * 32 + r16;
#pragma unroll
    for (int r = 0; r < 4; ++r) {
        QK[(rowb + r) * QKCOLS + colb] = f2bf(acc00[r]);
        QK[(rowb + r) * QKCOLS + colb + 16] = f2bf(acc01[r]);
        QK[(rowb + 16 + r) * QKCOLS + colb] = f2bf(acc10[r]);
        QK[(rowb + 16 + r) * QKCOLS + colb + 16] = f2bf(acc11[r]);
    }
}

// ---------------- colsum of V per (b,h): sumv[24][32] ----------------
__global__ __launch_bounds__(256) void colsum_kernel(const ushort_t* __restrict__ Xt,
                                                     float* __restrict__ sumv) {
    int bh = blockIdx.x;  // 0..23
    int b = bh / NH, h = bh % NH;
    int tid = threadIdx.x;
    int d = tid & 31, chunk = tid >> 5;  // 8 chunks
    const ushort_t* base = Xt + (long)b * NTOK * CDIM + h * HD + d;
    float s = 0.f;
    for (int n = chunk; n < NTOK; n += 8)
        s += bf2f(base[(long)n * CDIM]);
    __shared__ float red[8][32];
    red[chunk][d] = s;
    __syncthreads();
    if (chunk == 0) {
        float tot = 0.f;
#pragma unroll
        for (int i = 0; i < 8; ++i) tot += red[i][d];
        sumv[bh * HD + d] = tot;
    }
}

// ---------------- attention (flash-style, per (b,h,row-block)) ----------------
#define BR 128
#define BC 64
#define KS_PAD 40
#define VS_PAD 72
#define PS_PAD 72

__global__ __launch_bounds__(256) void attn_kernel(
    const ushort_t* __restrict__ QK, const ushort_t* __restrict__ Xt,
    const float* __restrict__ x, const float* __restrict__ sumv,
    const float* __restrict__ alpha, const float* __restrict__ beta,
    const float* __restrict__ gamma, float* __restrict__ out) {
    __shared__ __align__(16) ushort_t Ks[64][KS_PAD];
    __shared__ __align__(16) ushort_t VTs[32][VS_PAD];
    __shared__ __align__(16) ushort_t Ps[4][32][PS_PAD];

    int tid = threadIdx.x;
    int lane = tid & 63;
    int w = tid >> 6;
    int rb = blockIdx.x;  // 0..15 row block
    int h = blockIdx.y;   // 0..11
    int b = blockIdx.z;   // 0..1

    int r16 = lane & 15, g = lane >> 4;
    long bq = (long)b * NTOK;
    int n0 = rb * BR + w * 32;

    // Q fragments (pre-scaled at projection time)
    short8 qf0 = *reinterpret_cast<const short8*>(QK + (bq + n0 + r16) * QKCOLS + h * HD + g * 8);
    short8 qf1 = *reinterpret_cast<const short8*>(QK + (bq + n0 + 16 + r16) * QKCOLS + h * HD + g * 8);

    f32x4 acc[2][2] = {};
    float m_run[2][4], l_run[2][4];
#pragma unroll
    for (int rt = 0; rt < 2; ++rt)
#pragma unroll
        for (int r = 0; r < 4; ++r) {
            m_run[rt][r] = -1e30f;
            l_run[rt][r] = 0.f;
        }

    int srow = tid >> 2;   // 0..63
    int schunk = tid & 3;  // 0..3

    for (int tile = 0; tile < NTOK / BC; ++tile) {
        int m0 = tile * BC;
        // stage K tile [64][32] and V tile transposed [32][64]
        {
            short8 kv = *reinterpret_cast<const short8*>(
                QK + (bq + m0 + srow) * QKCOLS + CDIM + h * HD + schunk * 8);
            *reinterpret_cast<short8*>(&Ks[srow][schunk * 8]) = kv;
            short8 vv = *reinterpret_cast<const short8*>(
                Xt + (bq + m0 + srow) * CDIM + h * HD + schunk * 8);
#pragma unroll
            for (int i = 0; i < 8; ++i)
                VTs[schunk * 8 + i][srow] = (ushort_t)vv[i];
        }
        __syncthreads();

        // S = Q K^T : 2 row-tiles x 4 col-tiles of 16x16
        f32x4 s[2][4];
#pragma unroll
        for (int ct = 0; ct < 4; ++ct) {
            short8 kf = *reinterpret_cast<const short8*>(&Ks[ct * 16 + r16][g * 8]);
            s[0][ct] = __builtin_amdgcn_mfma_f32_16x16x32_bf16(qf0, kf, f32x4{}, 0, 0, 0);
            s[1][ct] = __builtin_amdgcn_mfma_f32_16x16x32_bf16(qf1, kf, f32x4{}, 0, 0, 0);
        }

        // online softmax update (row = (lane>>4)*4 + r within each 16-tile)
#pragma unroll
        for (int rt = 0; rt < 2; ++rt) {
#pragma unroll
            for (int r = 0; r < 4; ++r) {
                float tmax = fmaxf(fmaxf(s[rt][0][r], s[rt][1][r]),
                                   fmaxf(s[rt][2][r], s[rt][3][r]));
#pragma unroll
                for (int mask = 1; mask < 16; mask <<= 1)
                    tmax = fmaxf(tmax, __shfl_xor(tmax, mask));
                float mnew = fmaxf(m_run[rt][r], tmax);
                float corr = __expf(m_run[rt][r] - mnew);
                float rowsum = 0.f;
#pragma unroll
                for (int ct = 0; ct < 4; ++ct) {
                    float p = __expf(s[rt][ct][r] - mnew);
                    s[rt][ct][r] = p;
                    rowsum += p;
                }
#pragma unroll
                for (int mask = 1; mask < 16; mask <<= 1)
                    rowsum += __shfl_xor(rowsum, mask);
                l_run[rt][r] = l_run[rt][r] * corr + rowsum;
                m_run[rt][r] = mnew;
                acc[rt][0][r] *= corr;
                acc[rt][1][r] *= corr;
            }
        }

        // write P (bf16) to per-wave LDS region [32 rows][64 m]
#pragma unroll
        for (int rt = 0; rt < 2; ++rt)
#pragma unroll
            for (int ct = 0; ct < 4; ++ct)
#pragma unroll
                for (int r = 0; r < 4; ++r)
                    Ps[w][rt * 16 + g * 4 + r][ct * 16 + r16] = f2bf(s[rt][ct][r]);
        __syncthreads();

        // PV: O += P @ V
#pragma unroll
        for (int mt = 0; mt < 2; ++mt) {
            short8 pa0 = *reinterpret_cast<const short8*>(&Ps[w][r16][mt * 32 + g * 8]);
            short8 pa1 = *reinterpret_cast<const short8*>(&Ps[w][16 + r16][mt * 32 + g * 8]);
#pragma unroll
            for (int dt = 0; dt < 2; ++dt) {
                short8 vb = *reinterpret_cast<const short8*>(&VTs[dt * 16 + r16][mt * 32 + g * 8]);
                acc[0][dt] = __builtin_amdgcn_mfma_f32_16x16x32_bf16(pa0, vb, acc[0][dt], 0, 0, 0);
                acc[1][dt] = __builtin_amdgcn_mfma_f32_16x16x32_bf16(pa1, vb, acc[1][dt], 0, 0, 0);
            }
        }
        __syncthreads();
    }

    // epilogue: out = beta*softmax_out + alpha*v - (gamma/N)*colsum(v)
    float alpha_h = alpha[h], beta_h = beta[h], gamma_h = gamma[h];
    int bh = b * NH + h;
#pragma unroll
    for (int rt = 0; rt < 2; ++rt) {
#pragma unroll
        for (int dt = 0; dt < 2; ++dt) {
#pragma unroll
            for (int r = 0; r < 4; ++r) {
                int n = n0 + rt * 16 + g * 4 + r;
                int d = dt * 16 + r16;
                int c = h * HD + d;
                float sv = sumv[bh * HD + d] * (1.0f / NTOK);
                long xidx = ((long)(b * NFRAMES + (n >> 8)) * CDIM + c) * 256 + (n & 255);
                float vval = x[xidx];
                float val = beta_h * (acc[rt][dt][r] / l_run[rt][r]) + alpha_h * vval - gamma_h * sv;
                out[xidx] = val;
            }
        }
    }
}

extern "C" void kernel_launch(void* const* d_in, const int* in_sizes, int n_in,
                              void* d_out, int out_size, void* d_ws, size_t ws_size,
                              hipStream_t stream) {
    const float* x = (const float*)d_in[0];
    const float* qk_w = (const float*)d_in[1];
    const float* alpha = (const float*)d_in[2];
    const float* beta = (const float*)d_in[3];
    const float* gamma = (const float*)d_in[4];
    float* out = (float*)d_out;

    char* ws = (char*)d_ws;
    ushort_t* Xt = (ushort_t*)ws;                                    // 4096*384*2 = 3,145,728 B
    ushort_t* Wb = (ushort_t*)(ws + 3145728);                        // 768*384*2  =   589,824 B
    ushort_t* QK = (ushort_t*)(ws + 3145728 + 589824);               // 4096*768*2 = 6,291,456 B
    float* sumv = (float*)(ws + 3145728 + 589824 + 6291456);         // 24*32*4    =     3,072 B

    hipLaunchKernelGGL(pack_x_kernel, dim3(16, 12), dim3(256), 0, stream, x, Xt);
    hipLaunchKernelGGL(pack_w_kernel, dim3(1152), dim3(256), 0, stream, qk_w, Wb);
    hipLaunchKernelGGL(proj_kernel, dim3(768), dim3(256), 0, stream, Xt, Wb, QK);
    hipLaunchKernelGGL(colsum_kernel, dim3(24), dim3(256), 0, stream, Xt, sumv);
    hipLaunchKernelGGL(attn_kernel, dim3(16, 12, 2), dim3(256), 0, stream,
                       QK, Xt, x, sumv, alpha, beta, gamma, out);
}

// Round 2
// 121.368 us; speedup vs baseline: 1.5498x; 1.5498x over previous
//
#include <hip/hip_runtime.h>
#include <hip/hip_bf16.h>

typedef __attribute__((ext_vector_type(8))) short short8;
typedef __attribute__((ext_vector_type(4))) float f32x4;
typedef unsigned short ushort_t;

#define NFRAMES 8
#define HD 32
#define CDIM 384
#define NH 12
#define NTOK 2048
#define NROWS 4096
#define QKCOLS 768

static __device__ __forceinline__ ushort_t f2bf(float f) {
    __hip_bfloat16 h = __float2bfloat16(f);
    return *reinterpret_cast<ushort_t*>(&h);
}

// ---------------- pack x: [16,384,16,16] f32 -> Xt[4096][384] bf16, + per-frame colsums ----------------
__global__ __launch_bounds__(256) void pack_x_kernel(const float* __restrict__ x,
                                                     ushort_t* __restrict__ Xt,
                                                     float* __restrict__ psum) {
    __shared__ float lds[32 * 256];
    __shared__ float red[8][32];
    int bt = blockIdx.x;    // 0..15  (= b*8 + t)
    int cblk = blockIdx.y;  // 0..11  (= head h, since HD==32)
    int tid = threadIdx.x;  // 0..255
    int c0 = cblk * 32;
    const float* src = x + ((long)bt * CDIM + c0) * 256;
#pragma unroll
    for (int i = 0; i < 32; ++i)
        lds[i * 256 + tid] = src[i * 256 + tid];
    __syncthreads();
    int b = bt >> 3, t = bt & 7;
    long n = (long)b * NTOK + t * 256 + tid;
    uint4* dst = reinterpret_cast<uint4*>(Xt + n * CDIM + c0);
#pragma unroll
    for (int k = 0; k < 4; ++k) {
        unsigned int vv[4];
#pragma unroll
        for (int q = 0; q < 4; ++q) {
            ushort_t lo = f2bf(lds[(k * 8 + q * 2) * 256 + tid]);
            ushort_t hi = f2bf(lds[(k * 8 + q * 2 + 1) * 256 + tid]);
            vv[q] = (unsigned int)lo | ((unsigned int)hi << 16);
        }
        dst[k] = make_uint4(vv[0], vv[1], vv[2], vv[3]);
    }
    // per-frame column sums over this frame's 256 tokens (deterministic, no atomics)
    int ch = tid & 31, seg = tid >> 5;
    float s = 0.f;
#pragma unroll
    for (int j = 0; j < 32; ++j)
        s += lds[ch * 256 + seg * 32 + j];
    red[seg][ch] = s;
    __syncthreads();
    if (tid < 32) {
        float tot = 0.f;
#pragma unroll
        for (int i = 0; i < 8; ++i) tot += red[i][tid];
        psum[(bt * NH + cblk) * HD + tid] = tot;
    }
}

// ---------------- pack w: qk_w [768][384] f32 -> bf16, q-half pre-scaled ----------------
__global__ __launch_bounds__(256) void pack_w_kernel(const float* __restrict__ w,
                                                     ushort_t* __restrict__ Wb) {
    int idx = blockIdx.x * 256 + threadIdx.x;
    if (idx >= QKCOLS * CDIM) return;
    int j = idx / CDIM;
    float scale = (j < CDIM) ? 0.17677669529663687f : 1.0f;  // 32^-0.5 folded into Wq
    Wb[idx] = f2bf(w[idx] * scale);
}

// ---------------- projection: QK[4096][768] = Xt[4096][384] @ Wb^T ----------------
__global__ __launch_bounds__(256) void proj_kernel(const ushort_t* __restrict__ Xt,
                                                   const ushort_t* __restrict__ Wb,
                                                   ushort_t* __restrict__ QK) {
    int tid = threadIdx.x;
    int lane = tid & 63;
    int wid = blockIdx.x * 4 + (tid >> 6);  // 0..3071
    int mb = wid / 24, nb = wid % 24;       // 128 x 24 wave tiles of 32x32
    int r16 = lane & 15, g = lane >> 4;
    const short8* A0 = reinterpret_cast<const short8*>(Xt + (mb * 32 + r16) * CDIM + g * 8);
    const short8* A1 = reinterpret_cast<const short8*>(Xt + (mb * 32 + 16 + r16) * CDIM + g * 8);
    const short8* B0 = reinterpret_cast<const short8*>(Wb + (nb * 32 + r16) * CDIM + g * 8);
    const short8* B1 = reinterpret_cast<const short8*>(Wb + (nb * 32 + 16 + r16) * CDIM + g * 8);
    f32x4 acc00{}, acc01{}, acc10{}, acc11{};
#pragma unroll
    for (int kk = 0; kk < 12; ++kk) {
        short8 a0 = A0[kk * 4];
        short8 a1 = A1[kk * 4];
        short8 b0 = B0[kk * 4];
        short8 b1 = B1[kk * 4];
        acc00 = __builtin_amdgcn_mfma_f32_16x16x32_bf16(a0, b0, acc00, 0, 0, 0);
        acc01 = __builtin_amdgcn_mfma_f32_16x16x32_bf16(a0, b1, acc01, 0, 0, 0);
        acc10 = __builtin_amdgcn_mfma_f32_16x16x32_bf16(a1, b0, acc10, 0, 0, 0);
        acc11 = __builtin_amdgcn_mfma_f32_16x16x32_bf16(a1, b1, acc11, 0, 0, 0);
    }
    int rowb = mb * 32 + g * 4;
    int colb = nb * 32 + r16;
#pragma unroll
    for (int r = 0; r < 4; ++r) {
        QK[(rowb + r) * QKCOLS + colb] = f2bf(acc00[r]);
        QK[(rowb + r) * QKCOLS + colb + 16] = f2bf(acc01[r]);
        QK[(rowb + 16 + r) * QKCOLS + colb] = f2bf(acc10[r]);
        QK[(rowb + 16 + r) * QKCOLS + colb + 16] = f2bf(acc11[r]);
    }
}

// ---------------- attention (flash-style), BR=64, 4 waves x 16 rows ----------------
#define BC 64
#define KS_PAD 36
#define VS_PAD 66
#define PS_PAD 72

__global__ __launch_bounds__(256) void attn_kernel(
    const ushort_t* __restrict__ QK, const ushort_t* __restrict__ Xt,
    const float* __restrict__ x, const float* __restrict__ psum,
    const float* __restrict__ alpha, const float* __restrict__ beta,
    const float* __restrict__ gamma, float* __restrict__ out) {
    __shared__ __align__(16) ushort_t Ks[2][64][KS_PAD];
    __shared__ __align__(16) ushort_t VTs[2][32][VS_PAD];
    __shared__ __align__(16) ushort_t Ps[4][16][PS_PAD];

    int tid = threadIdx.x;
    int lane = tid & 63;
    int w = tid >> 6;
    // XCD-aware swizzle: 768 = 8 XCDs * 96; XCD g owns logical blocks [g*96, g*96+96)
    // = 3 consecutive (b,h) pairs -> K/V stay in one XCD's L2.
    int bid = blockIdx.x;
    int L = (bid & 7) * 96 + (bid >> 3);
    int rb = L & 31;   // 0..31 row block (64 rows)
    int bh = L >> 5;   // 0..23
    int h = bh % NH, b = bh / NH;

    int r16 = lane & 15, g = lane >> 4;
    long bq = (long)b * NTOK;
    int n0 = rb * 64 + w * 16;

    // Q fragment (pre-scaled at projection time): 16 rows x 32 k
    short8 qf = *reinterpret_cast<const short8*>(QK + (bq + n0 + r16) * QKCOLS + h * HD + g * 8);

    f32x4 acc[2] = {};
    float m_run[4], l_run[4];
#pragma unroll
    for (int r = 0; r < 4; ++r) { m_run[r] = -1e30f; l_run[r] = 0.f; }

    int srow = tid >> 2;   // 0..63
    int schunk = tid & 3;  // 0..3

    auto stage = [&](int tile, int buf) {
        int m0 = tile * BC;
        short8 kv = *reinterpret_cast<const short8*>(
            QK + (bq + m0 + srow) * QKCOLS + CDIM + h * HD + schunk * 8);
        *reinterpret_cast<short8*>(&Ks[buf][srow][schunk * 8]) = kv;
        short8 vv = *reinterpret_cast<const short8*>(
            Xt + (bq + m0 + srow) * CDIM + h * HD + schunk * 8);
#pragma unroll
        for (int i = 0; i < 8; ++i)
            VTs[buf][schunk * 8 + i][srow] = (ushort_t)vv[i];
    };

    stage(0, 0);
    __syncthreads();

    for (int tile = 0; tile < NTOK / BC; ++tile) {
        int cur = tile & 1;
        if (tile + 1 < NTOK / BC) stage(tile + 1, cur ^ 1);

        // S = Q K^T : 4 col-tiles of 16x16
        f32x4 s[4];
#pragma unroll
        for (int ct = 0; ct < 4; ++ct) {
            short8 kf = *reinterpret_cast<const short8*>(&Ks[cur][ct * 16 + r16][g * 8]);
            s[ct] = __builtin_amdgcn_mfma_f32_16x16x32_bf16(qf, kf, f32x4{}, 0, 0, 0);
        }

        // online softmax (row = g*4 + r, held by 16-lane group)
#pragma unroll
        for (int r = 0; r < 4; ++r) {
            float tmax = fmaxf(fmaxf(s[0][r], s[1][r]), fmaxf(s[2][r], s[3][r]));
#pragma unroll
            for (int mask = 1; mask < 16; mask <<= 1)
                tmax = fmaxf(tmax, __shfl_xor(tmax, mask));
            float mnew = fmaxf(m_run[r], tmax);
            float corr = __expf(m_run[r] - mnew);
            float rowsum = 0.f;
#pragma unroll
            for (int ct = 0; ct < 4; ++ct) {
                float p = __expf(s[ct][r] - mnew);
                s[ct][r] = p;
                rowsum += p;
            }
#pragma unroll
            for (int mask = 1; mask < 16; mask <<= 1)
                rowsum += __shfl_xor(rowsum, mask);
            l_run[r] = l_run[r] * corr + rowsum;
            m_run[r] = mnew;
            acc[0][r] *= corr;
            acc[1][r] *= corr;
        }

        // P -> per-wave LDS (no cross-wave hazard -> no barrier needed)
#pragma unroll
        for (int ct = 0; ct < 4; ++ct)
#pragma unroll
            for (int r = 0; r < 4; ++r)
                Ps[w][g * 4 + r][ct * 16 + r16] = f2bf(s[ct][r]);

        // PV: O += P @ V
#pragma unroll
        for (int mt = 0; mt < 2; ++mt) {
            short8 pa = *reinterpret_cast<const short8*>(&Ps[w][r16][mt * 32 + g * 8]);
#pragma unroll
            for (int dt = 0; dt < 2; ++dt) {
                short8 vb = *reinterpret_cast<const short8*>(&VTs[cur][dt * 16 + r16][mt * 32 + g * 8]);
                acc[dt] = __builtin_amdgcn_mfma_f32_16x16x32_bf16(pa, vb, acc[dt], 0, 0, 0);
            }
        }
        __syncthreads();
    }

    // epilogue: out = beta*softmax_out + alpha*v - (gamma/N)*colsum(v)
    float alpha_h = alpha[h], beta_h = beta[h], gamma_h = gamma[h];
#pragma unroll
    for (int dt = 0; dt < 2; ++dt) {
        int d = dt * 16 + r16;
        float sv = 0.f;
#pragma unroll
        for (int t = 0; t < 8; ++t)
            sv += psum[((b * NFRAMES + t) * NH + h) * HD + d];
        sv *= (1.0f / NTOK);
        int c = h * HD + d;
#pragma unroll
        for (int r = 0; r < 4; ++r) {
            int n = n0 + g * 4 + r;
            long xidx = ((long)(b * NFRAMES + (n >> 8)) * CDIM + c) * 256 + (n & 255);
            float vval = x[xidx];
            float val = beta_h * (acc[dt][r] / l_run[r]) + alpha_h * vval - gamma_h * sv;
            out[xidx] = val;
        }
    }
}

extern "C" void kernel_launch(void* const* d_in, const int* in_sizes, int n_in,
                              void* d_out, int out_size, void* d_ws, size_t ws_size,
                              hipStream_t stream) {
    const float* x = (const float*)d_in[0];
    const float* qk_w = (const float*)d_in[1];
    const float* alpha = (const float*)d_in[2];
    const float* beta = (const float*)d_in[3];
    const float* gamma = (const float*)d_in[4];
    float* out = (float*)d_out;

    char* ws = (char*)d_ws;
    ushort_t* Xt = (ushort_t*)ws;                              // 4096*384*2 = 3,145,728 B
    ushort_t* Wb = (ushort_t*)(ws + 3145728);                  // 768*384*2  =   589,824 B
    ushort_t* QK = (ushort_t*)(ws + 3145728 + 589824);         // 4096*768*2 = 6,291,456 B
    float* psum = (float*)(ws + 3145728 + 589824 + 6291456);   // 16*12*32*4 =    24,576 B

    hipLaunchKernelGGL(pack_x_kernel, dim3(16, 12), dim3(256), 0, stream, x, Xt, psum);
    hipLaunchKernelGGL(pack_w_kernel, dim3(1152), dim3(256), 0, stream, qk_w, Wb);
    hipLaunchKernelGGL(proj_kernel, dim3(768), dim3(256), 0, stream, Xt, Wb, QK);
    hipLaunchKernelGGL(attn_kernel, dim3(768), dim3(256), 0, stream,
                       QK, Xt, x, psum, alpha, beta, gamma, out);
}

// Round 3
// 63.287 us; speedup vs baseline: 2.9721x; 1.9177x over previous
//
#include <hip/hip_runtime.h>
#include <hip/hip_bf16.h>

typedef __attribute__((ext_vector_type(8))) short short8;
typedef __attribute__((ext_vector_type(4))) float f32x4;
typedef __attribute__((ext_vector_type(16))) float f32x16;
typedef __attribute__((ext_vector_type(4))) unsigned int uint4v;
typedef unsigned short ushort_t;
typedef unsigned int uint_t;

#define NFRAMES 8
#define HD 32
#define CDIM 384
#define NH 12
#define NTOK 2048
#define QKCOLS 768
// (1/sqrt(32)) * log2(e): fold softmax scale AND exp2 base-change into Wq
#define QSCALE 0.2550541213313367f

static __device__ __forceinline__ ushort_t f2bf(float f) {
    __hip_bfloat16 h = __float2bfloat16(f);
    return *reinterpret_cast<ushort_t*>(&h);
}
static __device__ __forceinline__ uint_t packbf2(float lo, float hi) {
    return (uint_t)f2bf(lo) | ((uint_t)f2bf(hi) << 16);
}
static __device__ __forceinline__ void glds16(const void* g, void* l) {
    __builtin_amdgcn_global_load_lds(
        (const __attribute__((address_space(1))) unsigned int*)g,
        (__attribute__((address_space(3))) unsigned int*)l, 16, 0, 0);
}

// ---------------- pack x: [16,384,16,16] f32 -> Xt[4096][384] bf16 + VFG fragments + psum ----------------
// VFG layout: [(b*12+h)][tile(64 kv)][slot][8 bf16], slot = (ks*2+hi)*32 + d,
// 16B = V[m0+ks*16+hi*8 .. +7][d]  (V^T row segment -> B-frag for mfma_32x32x16)
__global__ __launch_bounds__(256) void pack_x_kernel(const float* __restrict__ x,
                                                     ushort_t* __restrict__ Xt,
                                                     ushort_t* __restrict__ VFG,
                                                     float* __restrict__ psum) {
    __shared__ float lds[32 * 256];
    __shared__ float red[8][32];
    int bt = blockIdx.x;    // 0..15 (= b*8 + t)
    int cblk = blockIdx.y;  // 0..11 (= head h since HD==32)
    int tid = threadIdx.x;
    int c0 = cblk * 32;
    const float* src = x + ((long)bt * CDIM + c0) * 256;
#pragma unroll
    for (int i = 0; i < 32; ++i) lds[i * 256 + tid] = src[i * 256 + tid];
    __syncthreads();
    int b = bt >> 3, t = bt & 7;
    long n = (long)b * NTOK + t * 256 + tid;
    uint4* dst = reinterpret_cast<uint4*>(Xt + n * CDIM + c0);
#pragma unroll
    for (int k = 0; k < 4; ++k) {
        uint_t vv[4];
#pragma unroll
        for (int q = 0; q < 4; ++q)
            vv[q] = packbf2(lds[(k * 8 + q * 2) * 256 + tid], lds[(k * 8 + q * 2 + 1) * 256 + tid]);
        dst[k] = make_uint4(vv[0], vv[1], vv[2], vv[3]);
    }
    // V fragments (coalesced 16B per thread per kv-tile)
    int d = tid & 31, khi = tid >> 5;  // khi = ks*2+hi
#pragma unroll
    for (int kt = 0; kt < 4; ++kt) {
        const float* p0 = &lds[d * 256 + kt * 64 + khi * 8];
        float4 a = *(const float4*)p0;
        float4 bb = *(const float4*)(p0 + 4);
        uint4 o = make_uint4(packbf2(a.x, a.y), packbf2(a.z, a.w),
                             packbf2(bb.x, bb.y), packbf2(bb.z, bb.w));
        *(uint4*)((char*)VFG + ((size_t)((b * NH + cblk) * 32 + t * 4 + kt)) * 4096 + tid * 16) = o;
    }
    // per-frame column sums (deterministic)
    int ch = tid & 31, seg = tid >> 5;
    float s = 0.f;
#pragma unroll
    for (int j = 0; j < 32; ++j) s += lds[ch * 256 + seg * 32 + j];
    red[seg][ch] = s;
    __syncthreads();
    if (tid < 32) {
        float tot = 0.f;
#pragma unroll
        for (int i = 0; i < 8; ++i) tot += red[i][tid];
        psum[(bt * NH + cblk) * HD + tid] = tot;
    }
}

// ---------------- pack w: bf16, Q rows pre-scaled by QSCALE ----------------
__global__ __launch_bounds__(256) void pack_w_kernel(const float* __restrict__ w,
                                                     ushort_t* __restrict__ Wb) {
    int idx = blockIdx.x * 256 + threadIdx.x;
    if (idx >= QKCOLS * CDIM) return;
    int j = idx / CDIM;
    float scale = (j < CDIM) ? QSCALE : 1.0f;
    Wb[idx] = f2bf(w[idx] * scale);
}

// ---------------- projection: Qm[4096][384], K -> KFG fragment order ----------------
// KFG layout: [(b*12+h)][tile][slot][8 bf16], slot = sub*128 + khalf*64 + hi*32 + row,
// 16B = K[tile*64+sub*32+row][khalf*16+hi*8 .. +7]  (A-frag for mfma_32x32x16)
__global__ __launch_bounds__(256) void proj_kernel(const ushort_t* __restrict__ Xt,
                                                   const ushort_t* __restrict__ Wb,
                                                   ushort_t* __restrict__ Qm,
                                                   ushort_t* __restrict__ KFG) {
    int tid = threadIdx.x;
    int lane = tid & 63;
    int wid = blockIdx.x * 4 + (tid >> 6);
    int mb = wid / 24, nb = wid % 24;
    int r16 = lane & 15, g = lane >> 4;
    const short8* A0 = reinterpret_cast<const short8*>(Xt + (mb * 32 + r16) * CDIM + g * 8);
    const short8* A1 = reinterpret_cast<const short8*>(Xt + (mb * 32 + 16 + r16) * CDIM + g * 8);
    const short8* B0 = reinterpret_cast<const short8*>(Wb + (nb * 32 + r16) * CDIM + g * 8);
    const short8* B1 = reinterpret_cast<const short8*>(Wb + (nb * 32 + 16 + r16) * CDIM + g * 8);
    f32x4 acc00{}, acc01{}, acc10{}, acc11{};
#pragma unroll
    for (int kk = 0; kk < 12; ++kk) {
        short8 a0 = A0[kk * 4];
        short8 a1 = A1[kk * 4];
        short8 b0 = B0[kk * 4];
        short8 b1 = B1[kk * 4];
        acc00 = __builtin_amdgcn_mfma_f32_16x16x32_bf16(a0, b0, acc00, 0, 0, 0);
        acc01 = __builtin_amdgcn_mfma_f32_16x16x32_bf16(a0, b1, acc01, 0, 0, 0);
        acc10 = __builtin_amdgcn_mfma_f32_16x16x32_bf16(a1, b0, acc10, 0, 0, 0);
        acc11 = __builtin_amdgcn_mfma_f32_16x16x32_bf16(a1, b1, acc11, 0, 0, 0);
    }
    int rowb = mb * 32 + g * 4;
    int colb = nb * 32 + r16;
    if (nb < 12) {
#pragma unroll
        for (int r = 0; r < 4; ++r) {
            Qm[(rowb + r) * CDIM + colb] = f2bf(acc00[r]);
            Qm[(rowb + r) * CDIM + colb + 16] = f2bf(acc01[r]);
            Qm[(rowb + 16 + r) * CDIM + colb] = f2bf(acc10[r]);
            Qm[(rowb + 16 + r) * CDIM + colb + 16] = f2bf(acc11[r]);
        }
    } else {
        int hh = nb - 12;
        auto kput = [&](int nrow, int kd, float v) {
            int bb = nrow >> 11, nt = nrow & 2047;
            int tile = nt >> 6;
            int slot = ((nt >> 5) & 1) * 128 + (kd >> 4) * 64 + ((kd >> 3) & 1) * 32 + (nt & 31);
            KFG[(size_t)((bb * NH + hh) * 32 + tile) * 2048 + slot * 8 + (kd & 7)] = f2bf(v);
        };
        int kd0 = colb & 31;
#pragma unroll
        for (int r = 0; r < 4; ++r) {
            kput(rowb + r, kd0, acc00[r]);
            kput(rowb + r, kd0 + 16, acc01[r]);
            kput(rowb + 16 + r, kd0, acc10[r]);
            kput(rowb + 16 + r, kd0 + 16, acc11[r]);
        }
    }
}

// ---------------- attention: 32x32 swapped-QK^T, in-lane softmax (no max), KV-split wave pairs ----------------
__global__ __launch_bounds__(256, 3) void attn_kernel(
    const ushort_t* __restrict__ Qm, const ushort_t* __restrict__ KFG,
    const ushort_t* __restrict__ VFG, const float* __restrict__ x,
    const float* __restrict__ psum, const float* __restrict__ alpha,
    const float* __restrict__ beta, const float* __restrict__ gamma,
    float* __restrict__ out) {
    __shared__ __align__(16) char stag[2][16384];

    int tid = threadIdx.x, lane = tid & 63, w = tid >> 6;
    int bid = blockIdx.x;
    int L = (bid & 7) * 96 + (bid >> 3);  // XCD swizzle (768 = 8*96)
    int rb = L & 31, bh = L >> 5;
    int h = bh % NH, b = bh / NH;
    int j31 = lane & 31, hi = lane >> 5;
    long bq = (long)b * NTOK;
    int qb = rb * 64 + (w >> 1) * 32;  // this wave's 32 q-rows
    int kvpar = w & 1;                 // kv tile parity

    // Q B-frags (khalf 0/1): lane holds Q[qb+j31][khalf*16 + hi*8 .. +7]
    const ushort_t* qrow = Qm + (bq + qb + j31) * CDIM + h * HD + hi * 8;
    short8 qf0 = *(const short8*)(qrow);
    short8 qf1 = *(const short8*)(qrow + 16);

    f32x16 acc = {};
    float lp = 0.f;

    const char* kgbase = (const char*)KFG + (size_t)(bh * 32) * 4096 + tid * 16;
    const char* vgbase = (const char*)VFG + (size_t)(bh * 32) * 4096 + tid * 16;

    auto stage = [&](int it, int p) {
        int T0 = it * 2;
        glds16(kgbase + (size_t)T0 * 4096, &stag[p][0 * 4096 + w * 1024]);
        glds16(vgbase + (size_t)T0 * 4096, &stag[p][1 * 4096 + w * 1024]);
        glds16(kgbase + (size_t)(T0 + 1) * 4096, &stag[p][2 * 4096 + w * 1024]);
        glds16(vgbase + (size_t)(T0 + 1) * 4096, &stag[p][3 * 4096 + w * 1024]);
    };

    stage(0, 0);
    __syncthreads();

    for (int it = 0; it < 16; ++it) {
        int p = it & 1;
        if (it + 1 < 16) stage(it + 1, p ^ 1);

        const char* Kb = &stag[p][kvpar * 8192];
        const char* Vb = Kb + 4096;
        short8 kf00 = *(const short8*)(Kb + (0 * 128 + 0 * 64 + hi * 32 + j31) * 16);
        short8 kf01 = *(const short8*)(Kb + (0 * 128 + 1 * 64 + hi * 32 + j31) * 16);
        short8 kf10 = *(const short8*)(Kb + (1 * 128 + 0 * 64 + hi * 32 + j31) * 16);
        short8 kf11 = *(const short8*)(Kb + (1 * 128 + 1 * 64 + hi * 32 + j31) * 16);

        // S^T = K . Q^T : D[m][q], col=lane&31=q, row=crow(reg)+4*hi = m (within sub)
        f32x16 s0 = {}, s1 = {};
        s0 = __builtin_amdgcn_mfma_f32_32x32x16_bf16(kf00, qf0, s0, 0, 0, 0);
        s0 = __builtin_amdgcn_mfma_f32_32x32x16_bf16(kf01, qf1, s0, 0, 0, 0);
        s1 = __builtin_amdgcn_mfma_f32_32x32x16_bf16(kf10, qf0, s1, 0, 0, 0);
        s1 = __builtin_amdgcn_mfma_f32_32x32x16_bf16(kf11, qf1, s1, 0, 0, 0);

        // softmax numerator: P = 2^(S') (scale+log2e folded into Q), no max needed (|S'|<~1.2)
        uint_t pk0[8], pk1[8];
        float ls = 0.f;
#pragma unroll
        for (int pp = 0; pp < 8; ++pp) {
            float a0 = __builtin_amdgcn_exp2f(s0[2 * pp]);
            float a1 = __builtin_amdgcn_exp2f(s0[2 * pp + 1]);
            float b0 = __builtin_amdgcn_exp2f(s1[2 * pp]);
            float b1 = __builtin_amdgcn_exp2f(s1[2 * pp + 1]);
            ls += (a0 + a1) + (b0 + b1);
            pk0[pp] = packbf2(a0, a1);
            pk1[pp] = packbf2(b0, b1);
        }
        lp += ls;

        // redistribute P^T -> PA A-frags (exchange halves with lane^32) and PV
#pragma unroll
        for (int grp = 0; grp < 4; ++grp) {
            const uint_t* pks = (grp < 2) ? pk0 : pk1;
            int base = (grp & 1) * 4;
            uint_t o0 = pks[base], o1 = pks[base + 1], o2 = pks[base + 2], o3 = pks[base + 3];
            uint_t s0_ = hi ? o0 : o2, s1_ = hi ? o1 : o3;
            uint_t g0 = __shfl_xor(s0_, 32), g1 = __shfl_xor(s1_, 32);
            uint4v uu;
            uu[0] = hi ? g0 : o0;
            uu[1] = hi ? g1 : o1;
            uu[2] = hi ? o2 : g0;
            uu[3] = hi ? o3 : g1;
            short8 pa = __builtin_bit_cast(short8, uu);
            short8 vf = *(const short8*)(Vb + ((grp * 2 + hi) * 32 + j31) * 16);
            acc = __builtin_amdgcn_mfma_f32_32x32x16_bf16(pa, vf, acc, 0, 0, 0);
        }
        __syncthreads();
    }

    // merge wave-pair partials (pure add: no max-rescale needed)
    float* mrg = (float*)&stag[0][0];
    float* ab = mrg + (w >> 1) * 1088;  // 64 lanes * 17 (16 acc + lp); stride 17 = conflict-free
    if (kvpar) {
#pragma unroll
        for (int q = 0; q < 16; ++q) ab[lane * 17 + q] = acc[q];
        ab[lane * 17 + 16] = lp;
    }
    __syncthreads();
    if (!kvpar) {
#pragma unroll
        for (int q = 0; q < 16; ++q) acc[q] += ab[lane * 17 + q];
        float lsum = lp + ab[lane * 17 + 16];
        lsum += __shfl_xor(lsum, 32);
        float* Lb = mrg + 2176 + (w >> 1) * 32;
        if (!hi) Lb[j31] = lsum;
    }
    __syncthreads();
    if (!kvpar) {
        float* Lb = mrg + 2176 + (w >> 1) * 32;
        float alpha_h = alpha[h], beta_h = beta[h], gamma_h = gamma[h];
        int d = j31, c = h * HD + d;
        float sv = 0.f;
#pragma unroll
        for (int t = 0; t < NFRAMES; ++t) sv += psum[((b * NFRAMES + t) * NH + h) * HD + d];
        float gsv = gamma_h * sv * (1.0f / NTOK);
#pragma unroll
        for (int q = 0; q < 16; ++q) {
            int qrow = (q & 3) + 8 * (q >> 2) + 4 * hi;
            int n = qb + qrow;
            float linv = 1.0f / Lb[qrow];
            long xidx = ((long)(b * NFRAMES + (n >> 8)) * CDIM + c) * 256 + (n & 255);
            out[xidx] = beta_h * acc[q] * linv + alpha_h * x[xidx] - gsv;
        }
    }
}

extern "C" void kernel_launch(void* const* d_in, const int* in_sizes, int n_in,
                              void* d_out, int out_size, void* d_ws, size_t ws_size,
                              hipStream_t stream) {
    const float* x = (const float*)d_in[0];
    const float* qk_w = (const float*)d_in[1];
    const float* alpha = (const float*)d_in[2];
    const float* beta = (const float*)d_in[3];
    const float* gamma = (const float*)d_in[4];
    float* out = (float*)d_out;

    char* ws = (char*)d_ws;
    ushort_t* Xt = (ushort_t*)ws;                      // 3,145,728
    ushort_t* Wb = (ushort_t*)(ws + 3145728);          // 589,824
    ushort_t* Qm = (ushort_t*)(ws + 3735552);          // 3,145,728
    ushort_t* KFG = (ushort_t*)(ws + 6881280);         // 3,145,728
    ushort_t* VFG = (ushort_t*)(ws + 10027008);        // 3,145,728
    float* psum = (float*)(ws + 13172736);             // 24,576

    hipLaunchKernelGGL(pack_x_kernel, dim3(16, 12), dim3(256), 0, stream, x, Xt, VFG, psum);
    hipLaunchKernelGGL(pack_w_kernel, dim3(1152), dim3(256), 0, stream, qk_w, Wb);
    hipLaunchKernelGGL(proj_kernel, dim3(768), dim3(256), 0, stream, Xt, Wb, Qm, KFG);
    hipLaunchKernelGGL(attn_kernel, dim3(768), dim3(256), 0, stream,
                       Qm, KFG, VFG, x, psum, alpha, beta, gamma, out);
}

// Round 4
// 61.527 us; speedup vs baseline: 3.0571x; 1.0286x over previous
//
#include <hip/hip_runtime.h>
#include <hip/hip_bf16.h>

typedef __attribute__((ext_vector_type(8))) short short8;
typedef __attribute__((ext_vector_type(4))) float f32x4;
typedef __attribute__((ext_vector_type(16))) float f32x16;
typedef __attribute__((ext_vector_type(4))) unsigned int uint4v;
typedef unsigned short ushort_t;
typedef unsigned int uint_t;

#define NFRAMES 8
#define HD 32
#define CDIM 384
#define NH 12
#define NTOK 2048
#define QKCOLS 768
#define TILEB 2048  // one 32-kv (or 32-q) fragment tile = 128 slots * 16B
// (1/sqrt(32)) * log2(e): fold softmax scale AND exp2 base-change into Wq
#define QSCALE 0.2550541213313367f

static __device__ __forceinline__ ushort_t f2bf(float f) {
    __hip_bfloat16 h = __float2bfloat16(f);
    return *reinterpret_cast<ushort_t*>(&h);
}
static __device__ __forceinline__ uint_t packbf2(float lo, float hi) {
    return (uint_t)f2bf(lo) | ((uint_t)f2bf(hi) << 16);
}

// ---------------- pack x: [16,384,16,16] f32 -> Xt[4096][384] bf16 + VFG fragment tiles + psum ----------------
// VFG: [bh][64 tiles of 32 kv][128 slots][16B]; slot = (kh*2+hi)*32 + d,
// content = V[tile*32 + slot_c2*8 + j][d], j=0..7  (B-frag for mfma_32x32x16, 8 kv rows x 1 d col)
__global__ __launch_bounds__(256) void pack_x_kernel(const float* __restrict__ x,
                                                     ushort_t* __restrict__ Xt,
                                                     ushort_t* __restrict__ VFG,
                                                     float* __restrict__ psum) {
    __shared__ float lds[32 * 256];
    __shared__ float red[8][32];
    int bt = blockIdx.x;    // 0..15 (= b*8 + t)
    int h = blockIdx.y;     // 0..11 (head == 32-channel block)
    int tid = threadIdx.x;
    int c0 = h * 32;
    const float* src = x + ((long)bt * CDIM + c0) * 256;
#pragma unroll
    for (int i = 0; i < 32; ++i) lds[i * 256 + tid] = src[i * 256 + tid];
    __syncthreads();
    int b = bt >> 3, t = bt & 7;
    long n = (long)b * NTOK + t * 256 + tid;
    uint4* dst = reinterpret_cast<uint4*>(Xt + n * CDIM + c0);
#pragma unroll
    for (int k = 0; k < 4; ++k) {
        uint_t vv[4];
#pragma unroll
        for (int q = 0; q < 4; ++q)
            vv[q] = packbf2(lds[(k * 8 + q * 2) * 256 + tid], lds[(k * 8 + q * 2 + 1) * 256 + tid]);
        dst[k] = make_uint4(vv[0], vv[1], vv[2], vv[3]);
    }
    // V fragment tiles: 8 tiles of 32 kv per frame; 2 tiles per pass (256 thr * 16B = 4KB)
    int bh = b * NH + h;
#pragma unroll
    for (int pass = 0; pass < 4; ++pass) {
        int kt = pass * 2 + (tid >> 7);  // tile within frame 0..7
        int slot = tid & 127;
        int d = slot & 31, c2 = slot >> 5;
        const float* p0 = &lds[d * 256 + kt * 32 + c2 * 8];
        float4 a = *(const float4*)p0;
        float4 bb = *(const float4*)(p0 + 4);
        uint4 o = make_uint4(packbf2(a.x, a.y), packbf2(a.z, a.w),
                             packbf2(bb.x, bb.y), packbf2(bb.z, bb.w));
        *(uint4*)((char*)VFG + ((size_t)(bh * 64 + t * 8 + kt)) * TILEB + slot * 16) = o;
    }
    // per-frame column sums (deterministic)
    int ch = tid & 31, seg = tid >> 5;
    float s = 0.f;
#pragma unroll
    for (int j = 0; j < 32; ++j) s += lds[ch * 256 + seg * 32 + j];
    red[seg][ch] = s;
    __syncthreads();
    if (tid < 32) {
        float tot = 0.f;
#pragma unroll
        for (int i = 0; i < 8; ++i) tot += red[i][tid];
        psum[(bt * NH + h) * HD + tid] = tot;
    }
}

// ---------------- pack w: bf16, Q rows pre-scaled by QSCALE ----------------
__global__ __launch_bounds__(256) void pack_w_kernel(const float* __restrict__ w,
                                                     ushort_t* __restrict__ Wb) {
    int idx = blockIdx.x * 256 + threadIdx.x;
    if (idx >= QKCOLS * CDIM) return;
    int j = idx / CDIM;
    float scale = (j < CDIM) ? QSCALE : 1.0f;
    Wb[idx] = f2bf(w[idx] * scale);
}

// ---------------- projection: Q and K both emitted as fragment tiles (QFG/KFG) ----------------
// Tile slot s: row = s&31, hi = (s>>5)&1, khalf = s>>6; content = T[row][khalf*16 + hi*8 .. +7]
// A wave's 32x32 output tile == one 2KB fragment tile; transpose via per-wave LDS bounce.
__global__ __launch_bounds__(256) void proj_kernel(const ushort_t* __restrict__ Xt,
                                                   const ushort_t* __restrict__ Wb,
                                                   ushort_t* __restrict__ QFG,
                                                   ushort_t* __restrict__ KFG) {
    __shared__ __align__(16) ushort_t tb[4][32][40];  // padded: row stride 80B (16B-aligned)
    int tid = threadIdx.x;
    int lane = tid & 63;
    int w = tid >> 6;
    int wid = blockIdx.x * 4 + w;
    int mb = wid / 24, nb = wid % 24;  // mb: 128 row-tiles of 32 tokens; nb: 24 col-tiles
    int r16 = lane & 15, g = lane >> 4;
    const short8* A0 = reinterpret_cast<const short8*>(Xt + (mb * 32 + r16) * CDIM + g * 8);
    const short8* A1 = reinterpret_cast<const short8*>(Xt + (mb * 32 + 16 + r16) * CDIM + g * 8);
    const short8* B0 = reinterpret_cast<const short8*>(Wb + (nb * 32 + r16) * CDIM + g * 8);
    const short8* B1 = reinterpret_cast<const short8*>(Wb + (nb * 32 + 16 + r16) * CDIM + g * 8);
    f32x4 acc00{}, acc01{}, acc10{}, acc11{};
#pragma unroll
    for (int kk = 0; kk < 12; ++kk) {
        short8 a0 = A0[kk * 4];
        short8 a1 = A1[kk * 4];
        short8 b0 = B0[kk * 4];
        short8 b1 = B1[kk * 4];
        acc00 = __builtin_amdgcn_mfma_f32_16x16x32_bf16(a0, b0, acc00, 0, 0, 0);
        acc01 = __builtin_amdgcn_mfma_f32_16x16x32_bf16(a0, b1, acc01, 0, 0, 0);
        acc10 = __builtin_amdgcn_mfma_f32_16x16x32_bf16(a1, b0, acc10, 0, 0, 0);
        acc11 = __builtin_amdgcn_mfma_f32_16x16x32_bf16(a1, b1, acc11, 0, 0, 0);
    }
    // bounce through LDS: acc (16x16-frag layout) -> row-major [32][32] bf16 tile
#pragma unroll
    for (int r = 0; r < 4; ++r) {
        int lr = g * 4 + r;
        tb[w][lr][r16] = f2bf(acc00[r]);
        tb[w][lr][r16 + 16] = f2bf(acc01[r]);
        tb[w][lr + 16][r16] = f2bf(acc10[r]);
        tb[w][lr + 16][r16 + 16] = f2bf(acc11[r]);
    }
    // read fragment slots (lane and lane+64) and store coalesced
    short8 f0 = *(const short8*)&tb[w][lane & 31][(lane >> 5) * 8];
    short8 f1 = *(const short8*)&tb[w][lane & 31][16 + (lane >> 5) * 8];
    int bsel = mb >> 6;              // batch
    int tile = mb & 63;              // token tile within bh
    int hh = (nb < 12) ? nb : nb - 12;
    ushort_t* dstbuf = (nb < 12) ? QFG : KFG;
    char* base = (char*)dstbuf + ((size_t)((bsel * NH + hh) * 64 + tile)) * TILEB;
    *(short8*)(base + lane * 16) = f0;
    *(short8*)(base + 1024 + lane * 16) = f1;
}

// ---------------- attention: register-only pipeline, no LDS staging, no loop barriers ----------------
// 768 blocks = 24 bh * 32 row-blocks(64q). Waves: qsub=w>>1 (32 q-rows), kvpar=w&1 (kv half).
// Per wave: 32 tiles of 32 kv, 2-deep register prefetch.
__global__ __launch_bounds__(256) void attn_kernel(
    const ushort_t* __restrict__ QFG, const ushort_t* __restrict__ KFG,
    const ushort_t* __restrict__ VFG, const float* __restrict__ x,
    const float* __restrict__ psum, const float* __restrict__ alpha,
    const float* __restrict__ beta, const float* __restrict__ gamma,
    float* __restrict__ out) {
    __shared__ float mrg[2240];  // 2 * (64*17) partials + 2 * 32 L-rows

    int tid = threadIdx.x, lane = tid & 63, w = tid >> 6;
    int bid = blockIdx.x;
    int L = (bid & 7) * 96 + (bid >> 3);  // XCD swizzle (768 = 8*96, bijective)
    int rb = L & 31, bh = L >> 5;
    int h = bh % NH, b = bh / NH;
    int j31 = lane & 31, hi = lane >> 5;
    int qsub = w >> 1, kvpar = w & 1;
    int qb = rb * 64 + qsub * 32;

    const char* Qb = (const char*)QFG + ((size_t)(bh * 64 + rb * 2 + qsub)) * TILEB;
    short8 qf0 = *(const short8*)(Qb + lane * 16);
    short8 qf1 = *(const short8*)(Qb + 1024 + lane * 16);

    const char* Kbase = (const char*)KFG + (size_t)bh * 64 * TILEB + lane * 16;
    const char* Vbase = (const char*)VFG + (size_t)bh * 64 * TILEB + lane * 16;

    f32x16 acc = {};
    float lp = 0.f;

    short8 kA0, kA1, vA0, vA1, kB0, kB1, vB0, vB1;

#define LOADT(i, K0, K1, V0, V1)                                         \
    {                                                                    \
        size_t off = (size_t)(2 * (i) + kvpar) * TILEB;                  \
        K0 = *(const short8*)(Kbase + off);                              \
        K1 = *(const short8*)(Kbase + off + 1024);                       \
        V0 = *(const short8*)(Vbase + off);                              \
        V1 = *(const short8*)(Vbase + off + 1024);                       \
    }

#define COMPUTE(K0, K1, V0, V1)                                          \
    {                                                                    \
        f32x16 s = {};                                                   \
        s = __builtin_amdgcn_mfma_f32_32x32x16_bf16(K0, qf0, s, 0, 0, 0);\
        s = __builtin_amdgcn_mfma_f32_32x32x16_bf16(K1, qf1, s, 0, 0, 0);\
        float e[16];                                                     \
        _Pragma("unroll")                                                \
        for (int r = 0; r < 16; ++r) e[r] = __builtin_amdgcn_exp2f(s[r]);\
        lp += (((e[0] + e[1]) + (e[2] + e[3])) + ((e[4] + e[5]) + (e[6] + e[7]))) +  \
              (((e[8] + e[9]) + (e[10] + e[11])) + ((e[12] + e[13]) + (e[14] + e[15]))); \
        uint_t pk[8];                                                    \
        _Pragma("unroll")                                                \
        for (int j = 0; j < 8; ++j) pk[j] = packbf2(e[2 * j], e[2 * j + 1]); \
        _Pragma("unroll")                                                \
        for (int kh = 0; kh < 2; ++kh) {                                 \
            uint_t o0 = pk[kh * 4], o1 = pk[kh * 4 + 1];                 \
            uint_t o2 = pk[kh * 4 + 2], o3 = pk[kh * 4 + 3];             \
            uint_t s0_ = hi ? o0 : o2, s1_ = hi ? o1 : o3;               \
            uint_t g0 = __shfl_xor(s0_, 32), g1 = __shfl_xor(s1_, 32);   \
            uint4v uu;                                                   \
            uu[0] = hi ? g0 : o0;                                        \
            uu[1] = hi ? g1 : o1;                                        \
            uu[2] = hi ? o2 : g0;                                        \
            uu[3] = hi ? o3 : g1;                                        \
            short8 pa = __builtin_bit_cast(short8, uu);                  \
            acc = __builtin_amdgcn_mfma_f32_32x32x16_bf16(pa, (kh ? V1 : V0), acc, 0, 0, 0); \
        }                                                                \
    }

    LOADT(0, kA0, kA1, vA0, vA1);
#pragma unroll 2
    for (int i2 = 0; i2 < 16; ++i2) {
        int i = i2 * 2;
        if (i + 1 < 32) LOADT(i + 1, kB0, kB1, vB0, vB1);
        COMPUTE(kA0, kA1, vA0, vA1);
        if (i + 2 < 32) LOADT(i + 2, kA0, kA1, vA0, vA1);
        COMPUTE(kB0, kB1, vB0, vB1);
    }
#undef LOADT
#undef COMPUTE

    // merge wave-pair partials (pure add: no max-rescale in this softmax form)
    float* ab = mrg + qsub * 1088;  // 64 lanes * 17 floats, stride 17 = conflict-free
    if (kvpar) {
#pragma unroll
        for (int q = 0; q < 16; ++q) ab[lane * 17 + q] = acc[q];
        ab[lane * 17 + 16] = lp;
    }
    __syncthreads();
    float* Lb = mrg + 2176 + qsub * 32;
    if (!kvpar) {
#pragma unroll
        for (int q = 0; q < 16; ++q) acc[q] += ab[lane * 17 + q];
        float lsum = lp + ab[lane * 17 + 16];
        lsum += __shfl_xor(lsum, 32);
        if (!hi) Lb[j31] = lsum;
    }
    __syncthreads();
    if (!kvpar) {
        float alpha_h = alpha[h], beta_h = beta[h], gamma_h = gamma[h];
        int d = j31, c = h * HD + d;
        float sv = 0.f;
#pragma unroll
        for (int t = 0; t < NFRAMES; ++t) sv += psum[((b * NFRAMES + t) * NH + h) * HD + d];
        float gsv = gamma_h * sv * (1.0f / NTOK);
#pragma unroll
        for (int q = 0; q < 16; ++q) {
            int qrow = (q & 3) + 8 * (q >> 2) + 4 * hi;
            int n = qb + qrow;
            float linv = 1.0f / Lb[qrow];
            long xidx = ((long)(b * NFRAMES + (n >> 8)) * CDIM + c) * 256 + (n & 255);
            out[xidx] = beta_h * acc[q] * linv + alpha_h * x[xidx] - gsv;
        }
    }
}

extern "C" void kernel_launch(void* const* d_in, const int* in_sizes, int n_in,
                              void* d_out, int out_size, void* d_ws, size_t ws_size,
                              hipStream_t stream) {
    const float* x = (const float*)d_in[0];
    const float* qk_w = (const float*)d_in[1];
    const float* alpha = (const float*)d_in[2];
    const float* beta = (const float*)d_in[3];
    const float* gamma = (const float*)d_in[4];
    float* out = (float*)d_out;

    char* ws = (char*)d_ws;
    ushort_t* Xt = (ushort_t*)ws;                    // 3,145,728
    ushort_t* Wb = (ushort_t*)(ws + 3145728);        // 589,824
    ushort_t* QFG = (ushort_t*)(ws + 3735552);       // 3,145,728
    ushort_t* KFG = (ushort_t*)(ws + 6881280);       // 3,145,728
    ushort_t* VFG = (ushort_t*)(ws + 10027008);      // 3,145,728
    float* psum = (float*)(ws + 13172736);           // 24,576

    hipLaunchKernelGGL(pack_x_kernel, dim3(16, 12), dim3(256), 0, stream, x, Xt, VFG, psum);
    hipLaunchKernelGGL(pack_w_kernel, dim3(1152), dim3(256), 0, stream, qk_w, Wb);
    hipLaunchKernelGGL(proj_kernel, dim3(768), dim3(256), 0, stream, Xt, Wb, QFG, KFG);
    hipLaunchKernelGGL(attn_kernel, dim3(768), dim3(256), 0, stream,
                       QFG, KFG, VFG, x, psum, alpha, beta, gamma, out);
}

// Round 5
// 56.544 us; speedup vs baseline: 3.3265x; 1.0881x over previous
//
#include <hip/hip_runtime.h>
#include <hip/hip_bf16.h>

typedef __attribute__((ext_vector_type(8))) short short8;
typedef __attribute__((ext_vector_type(4))) float f32x4;
typedef __attribute__((ext_vector_type(2))) float f32x2;
typedef __attribute__((ext_vector_type(16))) float f32x16;
typedef __attribute__((ext_vector_type(4))) unsigned int uint4v;
typedef unsigned short ushort_t;
typedef unsigned int uint_t;

#define NFRAMES 8
#define HD 32
#define CDIM 384
#define NH 12
#define NTOK 2048
#define QKCOLS 768
#define TILEB 2048  // one 32-row fragment tile = 128 slots * 16B
// (1/sqrt(32)) * log2(e): fold softmax scale AND exp2 base-change into Wq
#define QSCALE 0.2550541213313367f

static __device__ __forceinline__ ushort_t f2bf(float f) {
    __hip_bfloat16 h = __float2bfloat16(f);
    return *reinterpret_cast<ushort_t*>(&h);
}
static __device__ __forceinline__ uint_t packbf2(float lo, float hi) {
    return (uint_t)f2bf(lo) | ((uint_t)f2bf(hi) << 16);
}

// ---------------- fused pack: x -> Xt + VFG + psum ; qk_w -> Wb ----------------
__global__ __launch_bounds__(256) void pack_kernel(const float* __restrict__ x,
                                                   const float* __restrict__ qk_w,
                                                   ushort_t* __restrict__ Xt,
                                                   ushort_t* __restrict__ VFG,
                                                   float* __restrict__ psum,
                                                   ushort_t* __restrict__ Wb) {
    int tid = threadIdx.x;
    int bid = blockIdx.x;
    if (bid >= 192) {
        // pack_w: 144 blocks, 8 elements/thread
        int vid = (bid - 192) * 256 + tid;  // 0..36863
        int j = vid / 48;                   // output row 0..767
        float scale = (j < CDIM) ? QSCALE : 1.0f;
        const float* src = qk_w + vid * 8;
        float4 a = *(const float4*)src;
        float4 b = *(const float4*)(src + 4);
        uint4 o = make_uint4(packbf2(a.x * scale, a.y * scale), packbf2(a.z * scale, a.w * scale),
                             packbf2(b.x * scale, b.y * scale), packbf2(b.z * scale, b.w * scale));
        *(uint4*)(Wb + vid * 8) = o;
        return;
    }
    __shared__ float lds[32 * 256];
    __shared__ float red[8][32];
    int bt = bid & 15;  // b*8 + t
    int h = bid >> 4;   // head
    int c0 = h * 32;
    const float* src = x + ((long)bt * CDIM + c0) * 256;
#pragma unroll
    for (int i = 0; i < 32; ++i) lds[i * 256 + tid] = src[i * 256 + tid];
    __syncthreads();
    int b = bt >> 3, t = bt & 7;
    long n = (long)b * NTOK + t * 256 + tid;
    uint4* dst = reinterpret_cast<uint4*>(Xt + n * CDIM + c0);
#pragma unroll
    for (int k = 0; k < 4; ++k) {
        uint_t vv[4];
#pragma unroll
        for (int q = 0; q < 4; ++q)
            vv[q] = packbf2(lds[(k * 8 + q * 2) * 256 + tid], lds[(k * 8 + q * 2 + 1) * 256 + tid]);
        dst[k] = make_uint4(vv[0], vv[1], vv[2], vv[3]);
    }
    // V fragment tiles: slot = (kh*2+hi)*32 + d ; content V[tile*32 + (kh*2+hi)*8 + j][d]
    int bh = b * NH + h;
#pragma unroll
    for (int pass = 0; pass < 4; ++pass) {
        int kt = pass * 2 + (tid >> 7);
        int slot = tid & 127;
        int d = slot & 31, c2 = slot >> 5;
        const float* p0 = &lds[d * 256 + kt * 32 + c2 * 8];
        float4 a = *(const float4*)p0;
        float4 bb = *(const float4*)(p0 + 4);
        uint4 o = make_uint4(packbf2(a.x, a.y), packbf2(a.z, a.w),
                             packbf2(bb.x, bb.y), packbf2(bb.z, bb.w));
        *(uint4*)((char*)VFG + ((size_t)(bh * 64 + t * 8 + kt)) * TILEB + slot * 16) = o;
    }
    // per-frame column sums
    int ch = tid & 31, seg = tid >> 5;
    float s = 0.f;
#pragma unroll
    for (int j = 0; j < 32; ++j) s += lds[ch * 256 + seg * 32 + j];
    red[seg][ch] = s;
    __syncthreads();
    if (tid < 32) {
        float tot = 0.f;
#pragma unroll
        for (int i = 0; i < 8; ++i) tot += red[i][tid];
        psum[(bt * NH + h) * HD + tid] = tot;
    }
}

// ---------------- projection (32x32x16 MFMA): Q/K emitted as fragment tiles ----------------
// Tile slot s: row = s&31, hi = (s>>5)&1, khalf = s>>6; content = T[row][khalf*16 + hi*8 .. +7]
__global__ __launch_bounds__(256) void proj_kernel(const ushort_t* __restrict__ Xt,
                                                   const ushort_t* __restrict__ Wb,
                                                   ushort_t* __restrict__ QFG,
                                                   ushort_t* __restrict__ KFG) {
    __shared__ __align__(16) ushort_t tb[4][32][40];
    int tid = threadIdx.x;
    int lane = tid & 63;
    int w = tid >> 6;
    int wid = blockIdx.x * 4 + w;
    int mb = wid / 24, nb = wid % 24;
    int j31 = lane & 31, hi = lane >> 5;
    const char* Arow = (const char*)(Xt + (mb * 32 + j31) * CDIM + hi * 8);
    const char* Brow = (const char*)(Wb + (nb * 32 + j31) * CDIM + hi * 8);
    f32x16 acc = {};
#pragma unroll
    for (int k16 = 0; k16 < 24; ++k16) {
        short8 a = *(const short8*)(Arow + k16 * 32);
        short8 bb = *(const short8*)(Brow + k16 * 32);
        acc = __builtin_amdgcn_mfma_f32_32x32x16_bf16(a, bb, acc, 0, 0, 0);
    }
    // bounce: D[row=crow(q,hi)][col=j31] -> row-major [32][32]
#pragma unroll
    for (int q = 0; q < 16; ++q) {
        int row = (q & 3) + 8 * (q >> 2) + 4 * hi;
        tb[w][row][j31] = f2bf(acc[q]);
    }
    short8 f0 = *(const short8*)&tb[w][j31][hi * 8];
    short8 f1 = *(const short8*)&tb[w][j31][16 + hi * 8];
    int bsel = mb >> 6;
    int tile = mb & 63;
    int hh = (nb < 12) ? nb : nb - 12;
    ushort_t* dstbuf = (nb < 12) ? QFG : KFG;
    char* base = (char*)dstbuf + ((size_t)((bsel * NH + hh) * 64 + tile)) * TILEB;
    *(short8*)(base + lane * 16) = f0;
    *(short8*)(base + 1024 + lane * 16) = f1;
}

// ---------------- attention: register pipeline, 4-way KV split, permlane P-redistribute ----------------
// grid 1536 = 24 bh * 64 q-tiles(32q). 4 waves/block = 4 kv-quarters of 16 tiles (32 kv each).
__global__ __launch_bounds__(256) void attn_kernel(
    const ushort_t* __restrict__ QFG, const ushort_t* __restrict__ KFG,
    const ushort_t* __restrict__ VFG, const float* __restrict__ x,
    const float* __restrict__ psum, const float* __restrict__ alpha,
    const float* __restrict__ beta, const float* __restrict__ gamma,
    float* __restrict__ out) {
    __shared__ float mrg[3 * 1088 + 32];

    int tid = threadIdx.x, lane = tid & 63, w = tid >> 6;
    int bid = blockIdx.x;
    int L = (bid & 7) * 192 + (bid >> 3);  // XCD swizzle, 1536 = 8*192, bijective
    int rb = L & 63, bh = L >> 6;
    int h = bh % NH, b = bh / NH;
    int j31 = lane & 31, hi = lane >> 5;
    int qb = rb * 32;

    const char* Qb = (const char*)QFG + ((size_t)(bh * 64 + rb)) * TILEB;
    short8 qf0 = *(const short8*)(Qb + lane * 16);
    short8 qf1 = *(const short8*)(Qb + 1024 + lane * 16);

    const char* Kbase = (const char*)KFG + ((size_t)(bh * 64 + w * 16)) * TILEB + lane * 16;
    const char* Vbase = (const char*)VFG + ((size_t)(bh * 64 + w * 16)) * TILEB + lane * 16;

    f32x16 acc = {};
    f32x2 lp2 = {};

    short8 kA0, kA1, vA0, vA1, kB0, kB1, vB0, vB1;

#define LOADT(i, K0, K1, V0, V1)                              \
    {                                                         \
        size_t off = (size_t)(i)*TILEB;                       \
        K0 = *(const short8*)(Kbase + off);                   \
        K1 = *(const short8*)(Kbase + off + 1024);            \
        V0 = *(const short8*)(Vbase + off);                   \
        V1 = *(const short8*)(Vbase + off + 1024);            \
    }

#define COMPUTE(K0, K1, V0, V1)                                                    \
    {                                                                              \
        f32x16 s = {};                                                             \
        s = __builtin_amdgcn_mfma_f32_32x32x16_bf16(K0, qf0, s, 0, 0, 0);          \
        s = __builtin_amdgcn_mfma_f32_32x32x16_bf16(K1, qf1, s, 0, 0, 0);          \
        uint_t pk[8];                                                              \
        _Pragma("unroll")                                                          \
        for (int j = 0; j < 8; ++j) {                                              \
            float e0 = __builtin_amdgcn_exp2f(s[2 * j]);                           \
            float e1 = __builtin_amdgcn_exp2f(s[2 * j + 1]);                       \
            uint_t u0 = __builtin_bit_cast(uint_t, e0) + 0x8000u;                  \
            uint_t u1 = __builtin_bit_cast(uint_t, e1) + 0x8000u;                  \
            pk[j] = __builtin_amdgcn_perm(u1, u0, 0x07060302u);                    \
            f32x2 ee;                                                              \
            ee[0] = e0;                                                            \
            ee[1] = e1;                                                            \
            lp2 += ee;                                                             \
        }                                                                          \
        _Pragma("unroll")                                                          \
        for (int kh = 0; kh < 2; ++kh) {                                           \
            uint_t o0 = pk[kh * 4], o1 = pk[kh * 4 + 1];                           \
            uint_t o2 = pk[kh * 4 + 2], o3 = pk[kh * 4 + 3];                       \
            auto r02 = __builtin_amdgcn_permlane32_swap(o2, o0, false, false);     \
            auto r13 = __builtin_amdgcn_permlane32_swap(o3, o1, false, false);     \
            uint4v uu;                                                             \
            uu[0] = r02[1]; /* {o0_lo || o2_lo} */                                 \
            uu[1] = r13[1]; /* {o1_lo || o3_lo} */                                 \
            uu[2] = r02[0]; /* {o0_hi || o2_hi} */                                 \
            uu[3] = r13[0]; /* {o1_hi || o3_hi} */                                 \
            short8 pa = __builtin_bit_cast(short8, uu);                            \
            acc = __builtin_amdgcn_mfma_f32_32x32x16_bf16(pa, (kh ? V1 : V0), acc, 0, 0, 0); \
        }                                                                          \
    }

    LOADT(0, kA0, kA1, vA0, vA1);
#pragma unroll
    for (int i2 = 0; i2 < 8; ++i2) {
        int i = i2 * 2;
        if (i + 1 < 16) LOADT(i + 1, kB0, kB1, vB0, vB1);
        COMPUTE(kA0, kA1, vA0, vA1);
        if (i + 2 < 16) LOADT(i + 2, kA0, kA1, vA0, vA1);
        COMPUTE(kB0, kB1, vB0, vB1);
    }
#undef LOADT
#undef COMPUTE

    float lp = lp2[0] + lp2[1];

    // merge 4 kv-quarter partials (pure add; no max-rescale in this softmax form)
    if (w) {
        float* ab = mrg + (w - 1) * 1088;
#pragma unroll
        for (int q = 0; q < 16; ++q) ab[lane * 17 + q] = acc[q];
        ab[lane * 17 + 16] = lp;
    }
    __syncthreads();
    if (w == 0) {
#pragma unroll
        for (int q = 0; q < 16; ++q)
            acc[q] += mrg[lane * 17 + q] + mrg[1088 + lane * 17 + q] + mrg[2176 + lane * 17 + q];
        float lsum = lp + mrg[lane * 17 + 16] + mrg[1088 + lane * 17 + 16] + mrg[2176 + lane * 17 + 16];
        lsum += __shfl_xor(lsum, 32);
        float* Lb = mrg + 3 * 1088;
        if (!hi) Lb[j31] = lsum;
        float alpha_h = alpha[h], beta_h = beta[h], gamma_h = gamma[h];
        int d = j31, c = h * HD + d;
        float sv = 0.f;
#pragma unroll
        for (int t = 0; t < NFRAMES; ++t) sv += psum[((b * NFRAMES + t) * NH + h) * HD + d];
        float gsv = gamma_h * sv * (1.0f / NTOK);
#pragma unroll
        for (int q = 0; q < 16; ++q) {
            int qrow = (q & 3) + 8 * (q >> 2) + 4 * hi;
            int n = qb + qrow;
            float linv = 1.0f / Lb[qrow];
            long xidx = ((long)(b * NFRAMES + (n >> 8)) * CDIM + c) * 256 + (n & 255);
            out[xidx] = beta_h * acc[q] * linv + alpha_h * x[xidx] - gsv;
        }
    }
}

extern "C" void kernel_launch(void* const* d_in, const int* in_sizes, int n_in,
                              void* d_out, int out_size, void* d_ws, size_t ws_size,
                              hipStream_t stream) {
    const float* x = (const float*)d_in[0];
    const float* qk_w = (const float*)d_in[1];
    const float* alpha = (const float*)d_in[2];
    const float* beta = (const float*)d_in[3];
    const float* gamma = (const float*)d_in[4];
    float* out = (float*)d_out;

    char* ws = (char*)d_ws;
    ushort_t* Xt = (ushort_t*)ws;                    // 3,145,728
    ushort_t* Wb = (ushort_t*)(ws + 3145728);        // 589,824
    ushort_t* QFG = (ushort_t*)(ws + 3735552);       // 3,145,728
    ushort_t* KFG = (ushort_t*)(ws + 6881280);       // 3,145,728
    ushort_t* VFG = (ushort_t*)(ws + 10027008);      // 3,145,728
    float* psum = (float*)(ws + 13172736);           // 24,576

    hipLaunchKernelGGL(pack_kernel, dim3(336), dim3(256), 0, stream, x, qk_w, Xt, VFG, psum, Wb);
    hipLaunchKernelGGL(proj_kernel, dim3(768), dim3(256), 0, stream, Xt, Wb, QFG, KFG);
    hipLaunchKernelGGL(attn_kernel, dim3(1536), dim3(256), 0, stream,
                       QFG, KFG, VFG, x, psum, alpha, beta, gamma, out);
}